// Round 6
// baseline (736.549 us; speedup 1.0000x reference)
//
#include <hip/hip_runtime.h>

// Sizes
#define Gg   128
#define N1   512
#define FH   128
#define K1   256
#define K2   128

typedef unsigned short ush;
typedef __bf16 bf16x8 __attribute__((ext_vector_type(8)));
typedef float  floatx4 __attribute__((ext_vector_type(4)));

__device__ inline float wredsum(float v) {
#pragma unroll
    for (int o = 32; o; o >>= 1) v += __shfl_xor(v, o, 64);
    return v;
}
__device__ inline float wredmax(float v) {
#pragma unroll
    for (int o = 32; o; o >>= 1) v = fmaxf(v, __shfl_xor(v, o, 64));
    return v;
}
__device__ inline ush bf_rne(float x) {
    unsigned u = __float_as_uint(x);
    return (ush)((u + 0x7fffu + ((u >> 16) & 1u)) >> 16);
}
__device__ inline float bf2f(ush u) { return __uint_as_float((unsigned)u << 16); }
__device__ inline void split3(float v, ush& h, ush& m, ush& l) {
    h = bf_rne(v);
    float r1 = v - bf2f(h);
    m = bf_rne(r1);
    l = bf_rne(r1 - bf2f(m));
}
__device__ __forceinline__ bf16x8 expand_bits(unsigned word, int quad) {
    unsigned byte = (word >> (quad * 8)) & 0xffu;
    unsigned au[4] __attribute__((aligned(16)));
    au[0] = ((byte & 1u)   ? 0x3F80u : 0u) | ((byte & 2u)   ? 0x3F800000u : 0u);
    au[1] = ((byte & 4u)   ? 0x3F80u : 0u) | ((byte & 8u)   ? 0x3F800000u : 0u);
    au[2] = ((byte & 16u)  ? 0x3F80u : 0u) | ((byte & 32u)  ? 0x3F800000u : 0u);
    au[3] = ((byte & 64u)  ? 0x3F80u : 0u) | ((byte & 128u) ? 0x3F800000u : 0u);
    return *(const bf16x8*)au;
}

// ---------------------------------------------------------------------------
// prep: degrees + 1-bit packed adjacency (adj values exactly 0/1)
// ---------------------------------------------------------------------------
__global__ __launch_bounds__(256) void k_prep(const float* __restrict__ adj,
        float* __restrict__ dinv_gcn, float* __restrict__ dinv_info,
        unsigned* __restrict__ adjbits) {
    int wave = threadIdx.x >> 6, lane = threadIdx.x & 63;
    long long row = (long long)blockIdx.x * 4 + wave;
    const float* ar = adj + row * N1;
    float s = 0.f;
    unsigned myw = 0;
#pragma unroll
    for (int c = 0; c < 8; ++c) {
        float v = ar[c * 64 + lane];
        s += v;
        unsigned long long mk = __ballot(v != 0.0f);
        unsigned lo = (unsigned)mk, hi = (unsigned)(mk >> 32);
        if ((lane >> 1) == c) myw = (lane & 1) ? hi : lo;
    }
    if (lane < 16) adjbits[row * 16 + lane] = myw;
    s = wredsum(s);
    if (lane == 0) {
        dinv_gcn[row]  = rsqrtf(s + 1.0f);
        dinv_info[row] = 1.0f / fmaxf(s, 1.0f);
    }
}

// ---------------------------------------------------------------------------
// Row-weight GEMM: C[M,128] = rs[row] * (A[M,128] @ W[128,128])  (rs optional)
// ---------------------------------------------------------------------------
__global__ __launch_bounds__(256) void k_gemm_rw(const float* __restrict__ A,
        const float* __restrict__ W, float* __restrict__ C,
        const float* __restrict__ rs) {
    __shared__ float Al[64][68];
    __shared__ float Wl[64][132];
    long long row0 = (long long)blockIdx.x * 64;
    int tid = threadIdx.x, tr = tid >> 4, tc = tid & 15;
    float acc[4][8] = {};
    for (int ch = 0; ch < 2; ++ch) {
        for (int p = tid; p < 1024; p += 256) {
            int r = p >> 4, c4 = p & 15;
            *(float4*)&Al[r][c4 * 4] = *(const float4*)(A + (row0 + r) * 128 + ch * 64 + c4 * 4);
        }
        for (int p = tid; p < 2048; p += 256) {
            int r = p >> 5, c4 = p & 31;
            *(float4*)&Wl[r][c4 * 4] = *(const float4*)(W + (ch * 64 + r) * 128 + c4 * 4);
        }
        __syncthreads();
        for (int k = 0; k < 64; ++k) {
            float4 w0 = *(const float4*)&Wl[k][tc * 8];
            float4 w1 = *(const float4*)&Wl[k][tc * 8 + 4];
            float w[8] = {w0.x, w0.y, w0.z, w0.w, w1.x, w1.y, w1.z, w1.w};
#pragma unroll
            for (int i = 0; i < 4; ++i) {
                float a = Al[tr * 4 + i][k];
#pragma unroll
                for (int j = 0; j < 8; ++j) acc[i][j] = fmaf(a, w[j], acc[i][j]);
            }
        }
        __syncthreads();
    }
#pragma unroll
    for (int i = 0; i < 4; ++i) {
        long long r = row0 + tr * 4 + i;
        float sc = rs ? rs[r] : 1.0f;
        *(float4*)(C + r * 128 + tc * 8)     = make_float4(sc * acc[i][0], sc * acc[i][1], sc * acc[i][2], sc * acc[i][3]);
        *(float4*)(C + r * 128 + tc * 8 + 4) = make_float4(sc * acc[i][4], sc * acc[i][5], sc * acc[i][6], sc * acc[i][7]);
    }
}

// ---------------------------------------------------------------------------
// transpose + 3-way bf16 split: feat[g*KD][128] fp32 -> T{hi,mid,lo}[g][128][KD]
// ---------------------------------------------------------------------------
template<int KD>
__global__ __launch_bounds__(256) void k_tsplit(const float* __restrict__ feat,
        ush* __restrict__ Thi, ush* __restrict__ Tmid, ush* __restrict__ Tlo) {
    __shared__ float tile[64 * 65];
    int b = blockIdx.x;                    // (G*KD/64) * 2
    int cb = b & 1;
    long long row0 = (long long)(b >> 1) * 64;
    int g = (int)(row0 / KD);
    int rk0 = (int)(row0 % KD);
    int t = threadIdx.x;
    {
        int r0 = t >> 4, c4 = t & 15;
#pragma unroll
        for (int i = 0; i < 4; ++i) {
            int r = r0 + i * 16;
            float4 v = *(const float4*)(feat + (row0 + r) * 128 + cb * 64 + c4 * 4);
            tile[r * 65 + c4 * 4 + 0] = v.x;
            tile[r * 65 + c4 * 4 + 1] = v.y;
            tile[r * 65 + c4 * 4 + 2] = v.z;
            tile[r * 65 + c4 * 4 + 3] = v.w;
        }
    }
    __syncthreads();
    int tf = t >> 2, chunk = t & 3;
    ush hbuf[16] __attribute__((aligned(16)));
    ush mbuf[16] __attribute__((aligned(16)));
    ush lbuf[16] __attribute__((aligned(16)));
#pragma unroll
    for (int i = 0; i < 16; ++i) {
        int m = chunk * 16 + i;
        split3(tile[m * 65 + tf], hbuf[i], mbuf[i], lbuf[i]);
    }
    long long obase = ((long long)g * 128 + cb * 64 + tf) * KD + rk0 + chunk * 16;
    *(uint4*)(Thi + obase)      = *(const uint4*)&hbuf[0];
    *(uint4*)(Thi + obase + 8)  = *(const uint4*)&hbuf[8];
    *(uint4*)(Tmid + obase)     = *(const uint4*)&mbuf[0];
    *(uint4*)(Tmid + obase + 8) = *(const uint4*)&mbuf[8];
    *(uint4*)(Tlo + obase)      = *(const uint4*)&lbuf[0];
    *(uint4*)(Tlo + obase + 8)  = *(const uint4*)&lbuf[8];
}

// ---------------------------------------------------------------------------
// helpers for pipelined MFMA kernels
// ---------------------------------------------------------------------------
__device__ __forceinline__ void loadB4(const ush* __restrict__ Bhi, const ush* __restrict__ Bmid,
        const ush* __restrict__ Blo, const long long* boff, int kk,
        bf16x8* h, bf16x8* m, bf16x8* l) {
#pragma unroll
    for (int tn = 0; tn < 4; ++tn) {
        h[tn] = *(const bf16x8*)(Bhi  + boff[tn] + kk);
        m[tn] = *(const bf16x8*)(Bmid + boff[tn] + kk);
        l[tn] = *(const bf16x8*)(Blo  + boff[tn] + kk);
    }
}
__device__ __forceinline__ void loadA2(const ush* __restrict__ Ahi, const ush* __restrict__ Amid,
        const ush* __restrict__ Alo, const long long* aoff, int kk,
        bf16x8* h, bf16x8* m, bf16x8* l) {
#pragma unroll
    for (int tm = 0; tm < 2; ++tm) {
        h[tm] = *(const bf16x8*)(Ahi  + aoff[tm] + kk);
        m[tm] = *(const bf16x8*)(Amid + aoff[tm] + kk);
        l[tm] = *(const bf16x8*)(Alo  + aoff[tm] + kk);
    }
}
__device__ __forceinline__ void aggb_step(const unsigned* bitsL, int a0r, int a1r, int kt, int quad,
        const bf16x8* Bh, const bf16x8* Bm, const bf16x8* Bl, floatx4 acc[2][4]) {
    bf16x8 af0 = expand_bits(bitsL[a0r + kt], quad);
    bf16x8 af1 = expand_bits(bitsL[a1r + kt], quad);
#pragma unroll
    for (int tn = 0; tn < 4; ++tn) {
        acc[0][tn] = __builtin_amdgcn_mfma_f32_16x16x32_bf16(af0, Bh[tn], acc[0][tn], 0, 0, 0);
        acc[1][tn] = __builtin_amdgcn_mfma_f32_16x16x32_bf16(af1, Bh[tn], acc[1][tn], 0, 0, 0);
        acc[0][tn] = __builtin_amdgcn_mfma_f32_16x16x32_bf16(af0, Bm[tn], acc[0][tn], 0, 0, 0);
        acc[1][tn] = __builtin_amdgcn_mfma_f32_16x16x32_bf16(af1, Bm[tn], acc[1][tn], 0, 0, 0);
        acc[0][tn] = __builtin_amdgcn_mfma_f32_16x16x32_bf16(af0, Bl[tn], acc[0][tn], 0, 0, 0);
        acc[1][tn] = __builtin_amdgcn_mfma_f32_16x16x32_bf16(af1, Bl[tn], acc[1][tn], 0, 0, 0);
    }
}
__device__ __forceinline__ void aggs_step(const bf16x8* Ah, const bf16x8* Am, const bf16x8* Al,
        const bf16x8* Bh, const bf16x8* Bm, const bf16x8* Bl, floatx4 acc[2][4]) {
#pragma unroll
    for (int tm = 0; tm < 2; ++tm)
#pragma unroll
    for (int tn = 0; tn < 4; ++tn) {
        floatx4 a = acc[tm][tn];
        a = __builtin_amdgcn_mfma_f32_16x16x32_bf16(Ah[tm], Bh[tn], a, 0, 0, 0);
        a = __builtin_amdgcn_mfma_f32_16x16x32_bf16(Ah[tm], Bm[tn], a, 0, 0, 0);
        a = __builtin_amdgcn_mfma_f32_16x16x32_bf16(Am[tm], Bh[tn], a, 0, 0, 0);
        a = __builtin_amdgcn_mfma_f32_16x16x32_bf16(Ah[tm], Bl[tn], a, 0, 0, 0);
        a = __builtin_amdgcn_mfma_f32_16x16x32_bf16(Al[tm], Bh[tn], a, 0, 0, 0);
        a = __builtin_amdgcn_mfma_f32_16x16x32_bf16(Am[tm], Bm[tn], a, 0, 0, 0);
        acc[tm][tn] = a;
    }
}

// ---------------------------------------------------------------------------
// bit-A MFMA aggregation (stage 1), register-pipelined B prefetch.
//  C = adj(bits) @ (Bhi+Bmid+Blo)[g][128][512]
//  EPI 0: outH = relu(di*(C+hx)+bias)   EPI 1: outS_i = sum_n |hx - C*di|
// ---------------------------------------------------------------------------
template<int EPI>
__global__ __launch_bounds__(256) void k_aggb(const unsigned* __restrict__ adjbits,
        const ush* __restrict__ Bhi, const ush* __restrict__ Bmid, const ush* __restrict__ Blo,
        const float* __restrict__ dvec, const float* __restrict__ hx,
        const float* __restrict__ bias, float* __restrict__ outH, float* __restrict__ outS) {
    __shared__ unsigned bitsL[64 * 17];
    __shared__ float sred[2][64];
    int b = blockIdx.x;                        // 1024
    int g  = (b & 7) + ((b >> 6) << 3);
    int rb = (b >> 3) & 7;
    int tid = threadIdx.x;
    int w = tid >> 6, lane = tid & 63;
    int wm = w >> 1, wn = w & 1;
    int ln = lane & 15, quad = lane >> 4;
    {
        int r = tid >> 2, w4 = (tid & 3) * 4;
        uint4 v = *(const uint4*)(adjbits + ((long long)(g * 512 + rb * 64 + r)) * 16 + w4);
        bitsL[r * 17 + w4 + 0] = v.x; bitsL[r * 17 + w4 + 1] = v.y;
        bitsL[r * 17 + w4 + 2] = v.z; bitsL[r * 17 + w4 + 3] = v.w;
    }
    __syncthreads();
    floatx4 acc[2][4];
#pragma unroll
    for (int i = 0; i < 2; ++i)
#pragma unroll
        for (int j = 0; j < 4; ++j) { floatx4 z = {0.f, 0.f, 0.f, 0.f}; acc[i][j] = z; }

    const long long bb = (long long)g * 128 * 512;
    long long boff[4];
#pragma unroll
    for (int tn = 0; tn < 4; ++tn)
        boff[tn] = bb + (long long)(wn * 64 + tn * 16 + ln) * 512 + quad * 8;
    int a0r = (wm * 32 + ln) * 17;
    int a1r = (wm * 32 + 16 + ln) * 17;

    bf16x8 Xh[4], Xm[4], Xl[4], Yh[4], Ym[4], Yl[4];
    loadB4(Bhi, Bmid, Blo, boff, 0, Xh, Xm, Xl);
    for (int kt = 0; kt < 16; kt += 2) {
        loadB4(Bhi, Bmid, Blo, boff, (kt + 1) * 32, Yh, Ym, Yl);
        aggb_step(bitsL, a0r, a1r, kt, quad, Xh, Xm, Xl, acc);
        if (kt + 2 < 16) loadB4(Bhi, Bmid, Blo, boff, (kt + 2) * 32, Xh, Xm, Xl);
        aggb_step(bitsL, a0r, a1r, kt + 1, quad, Yh, Ym, Yl, acc);
    }
    long long rowbase = (long long)g * 512 + rb * 64;
    if (EPI == 0) {
#pragma unroll
        for (int tm = 0; tm < 2; ++tm)
#pragma unroll
        for (int r = 0; r < 4; ++r) {
            long long grow = rowbase + wm * 32 + tm * 16 + quad * 4 + r;
            float di = dvec[grow];
#pragma unroll
            for (int tn = 0; tn < 4; ++tn) {
                int nc = wn * 64 + tn * 16 + ln;
                outH[grow * 128 + nc] =
                    fmaxf(fmaf(di, acc[tm][tn][r] + hx[grow * 128 + nc], bias[nc]), 0.f);
            }
        }
    } else {
#pragma unroll
        for (int tm = 0; tm < 2; ++tm)
#pragma unroll
        for (int r = 0; r < 4; ++r) {
            int ml = wm * 32 + tm * 16 + quad * 4 + r;
            long long grow = rowbase + ml;
            float di = dvec[grow];
            float v = 0.f;
#pragma unroll
            for (int tn = 0; tn < 4; ++tn) {
                int nc = wn * 64 + tn * 16 + ln;
                v += fabsf(hx[grow * 128 + nc] - acc[tm][tn][r] * di);
            }
            v += __shfl_xor(v, 1); v += __shfl_xor(v, 2);
            v += __shfl_xor(v, 4); v += __shfl_xor(v, 8);
            if (ln == 0) sred[wn][ml] = v;
        }
        __syncthreads();
        if (tid < 64) outS[rowbase + tid] = sred[0][tid] + sred[1][tid];
    }
}

// ---------------------------------------------------------------------------
// split-A x split-B MFMA aggregation (stages 2/3), register-pipelined.
//  C[i][f] = sum_j A(i,j) Y(j,f); A row-major splits [g][KD][KD];
//  Y^T k-major splits [g][128][KD]; 6 cross-term MFMAs (~fp32 accuracy).
//  EPI 0: outH = relu(di*(C+hx)+bias)   EPI 1: outS_i = sum_f |hx - C*di|
// ---------------------------------------------------------------------------
template<int KD, int EPI>
__global__ __launch_bounds__(256) void k_aggs(
        const ush* __restrict__ Ahi, const ush* __restrict__ Amid, const ush* __restrict__ Alo,
        const ush* __restrict__ Yhi, const ush* __restrict__ Ymid, const ush* __restrict__ Ylo,
        const float* __restrict__ dvec, const float* __restrict__ hx,
        const float* __restrict__ bias, float* __restrict__ outH, float* __restrict__ outS) {
    __shared__ float sred[2][64];
    constexpr int BPG = KD / 64;               // row-blocks per graph
    constexpr int KT = KD / 32;
    int b = blockIdx.x;                        // Gg * BPG
    int g  = (b & 7) + ((b / (8 * BPG)) << 3);
    int rb = (b >> 3) & (BPG - 1);
    int tid = threadIdx.x;
    int w = tid >> 6, lane = tid & 63;
    int wm = w >> 1, wn = w & 1;
    int ln = lane & 15, quad = lane >> 4;
    floatx4 acc[2][4];
#pragma unroll
    for (int i = 0; i < 2; ++i)
#pragma unroll
        for (int j = 0; j < 4; ++j) { floatx4 z = {0.f, 0.f, 0.f, 0.f}; acc[i][j] = z; }

    long long aoff[2], boff[4];
#pragma unroll
    for (int tm = 0; tm < 2; ++tm)
        aoff[tm] = ((long long)g * KD + rb * 64 + wm * 32 + tm * 16 + ln) * KD + quad * 8;
#pragma unroll
    for (int tn = 0; tn < 4; ++tn)
        boff[tn] = ((long long)g * 128 + wn * 64 + tn * 16 + ln) * KD + quad * 8;

    bf16x8 XAh[2], XAm[2], XAl[2], YAh[2], YAm[2], YAl[2];
    bf16x8 XBh[4], XBm[4], XBl[4], YBh[4], YBm[4], YBl[4];
    loadA2(Ahi, Amid, Alo, aoff, 0, XAh, XAm, XAl);
    loadB4(Yhi, Ymid, Ylo, boff, 0, XBh, XBm, XBl);
    for (int kt = 0; kt < KT; kt += 2) {
        loadA2(Ahi, Amid, Alo, aoff, (kt + 1) * 32, YAh, YAm, YAl);
        loadB4(Yhi, Ymid, Ylo, boff, (kt + 1) * 32, YBh, YBm, YBl);
        aggs_step(XAh, XAm, XAl, XBh, XBm, XBl, acc);
        if (kt + 2 < KT) {
            loadA2(Ahi, Amid, Alo, aoff, (kt + 2) * 32, XAh, XAm, XAl);
            loadB4(Yhi, Ymid, Ylo, boff, (kt + 2) * 32, XBh, XBm, XBl);
        }
        aggs_step(YAh, YAm, YAl, YBh, YBm, YBl, acc);
    }
    long long rowbase = (long long)g * KD + rb * 64;
    if (EPI == 0) {
#pragma unroll
        for (int tm = 0; tm < 2; ++tm)
#pragma unroll
        for (int r = 0; r < 4; ++r) {
            long long grow = rowbase + wm * 32 + tm * 16 + quad * 4 + r;
            float di = dvec[grow];
#pragma unroll
            for (int tn = 0; tn < 4; ++tn) {
                int nc = wn * 64 + tn * 16 + ln;
                outH[grow * 128 + nc] =
                    fmaxf(fmaf(di, acc[tm][tn][r] + hx[grow * 128 + nc], bias[nc]), 0.f);
            }
        }
    } else {
#pragma unroll
        for (int tm = 0; tm < 2; ++tm)
#pragma unroll
        for (int r = 0; r < 4; ++r) {
            int ml = wm * 32 + tm * 16 + quad * 4 + r;
            long long grow = rowbase + ml;
            float di = dvec[grow];
            float v = 0.f;
#pragma unroll
            for (int tn = 0; tn < 4; ++tn) {
                int nc = wn * 64 + tn * 16 + ln;
                v += fabsf(hx[grow * 128 + nc] - acc[tm][tn][r] * di);
            }
            v += __shfl_xor(v, 1); v += __shfl_xor(v, 2);
            v += __shfl_xor(v, 4); v += __shfl_xor(v, 8);
            if (ln == 0) sred[wn][ml] = v;
        }
        __syncthreads();
        if (tid < 64) outS[rowbase + tid] = sred[0][tid] + sred[1][tid];
    }
}

// ---------------------------------------------------------------------------
// top-k: bitonic sort of packed keys -> value desc, index asc (jax.lax.top_k)
// ---------------------------------------------------------------------------
template<int NT, int KSEL>
__global__ __launch_bounds__(256) void k_topk(const float* __restrict__ s, int* __restrict__ idx) {
    __shared__ unsigned long long keys[NT];
    int g = blockIdx.x;
    const float* sg = s + g * NT;
    for (int t = threadIdx.x; t < NT; t += 256) {
        unsigned int b = __float_as_uint(sg[t]);
        unsigned int ord = (b & 0x80000000u) ? ~b : (b | 0x80000000u);
        keys[t] = ((unsigned long long)(~ord) << 32) | (unsigned int)t;
    }
    __syncthreads();
    for (int k = 2; k <= NT; k <<= 1) {
        for (int j = k >> 1; j > 0; j >>= 1) {
            for (int i = threadIdx.x; i < NT; i += 256) {
                int l = i ^ j;
                if (l > i) {
                    bool dir = ((i & k) == 0);
                    unsigned long long a = keys[i], b2 = keys[l];
                    bool sw = dir ? (a > b2) : (a < b2);
                    if (sw) { keys[i] = b2; keys[l] = a; }
                }
            }
            __syncthreads();
        }
    }
    for (int t = threadIdx.x; t < KSEL; t += 256)
        idx[g * KSEL + t] = (int)(keys[t] & 0xffffffffu);
}

// ---------------------------------------------------------------------------
// gather pooled rows + attention dot products
// ---------------------------------------------------------------------------
template<int KK>
__global__ __launch_bounds__(256) void k_gather(const float* __restrict__ h, int srcN,
        const int* __restrict__ idx, const float* __restrict__ atts, const float* __restrict__ attd,
        float* __restrict__ xk, float* __restrict__ as_, float* __restrict__ ad_) {
    int wave = threadIdx.x >> 6, lane = threadIdx.x & 63;
    int r = blockIdx.x * 4 + wave;
    int g = r / KK;
    int j = idx[r];
    float2 v = *(const float2*)(h + ((long long)g * srcN + j) * 128 + lane * 2);
    *(float2*)(xk + (long long)r * 128 + lane * 2) = v;
    float2 sv = *(const float2*)(atts + lane * 2);
    float2 dv = *(const float2*)(attd + lane * 2);
    float ps = v.x * sv.x + v.y * sv.y;
    float pd = v.x * dv.x + v.y * dv.y;
    ps = wredsum(ps); pd = wredsum(pd);
    if (lane == 0) { as_[r] = ps; ad_[r] = pd; }
}

// ---------------------------------------------------------------------------
// attention stage-1 (bit adjacency): softmax(leaky(as_i+ad_j)+bit) ->
// dense a1 + row-major 3-splits (A-operand layout) + deg epilogues
// ---------------------------------------------------------------------------
__global__ __launch_bounds__(256) void k_attn1b(const unsigned* __restrict__ adjbits,
        const int* __restrict__ idx, const float* __restrict__ as_, const float* __restrict__ ad_,
        float* __restrict__ a1, ush* __restrict__ Ahi, ush* __restrict__ Amid, ush* __restrict__ Alo,
        float* __restrict__ dgo, float* __restrict__ dio) {
    __shared__ int   idxL[K1];
    __shared__ float adL[K1];
    __shared__ unsigned bitsW[4][20];
    __shared__ float rowL[4][K1];
    int g = blockIdx.x / (K1 / 4);
    int wave = threadIdx.x >> 6, lane = threadIdx.x & 63;
    int i = (blockIdx.x % (K1 / 4)) * 4 + wave;
    for (int t = threadIdx.x; t < K1; t += 256) { idxL[t] = idx[g * K1 + t]; adL[t] = ad_[g * K1 + t]; }
    __syncthreads();
    int ri = idxL[i];
    if (lane < 4) {
        uint4 v = *(const uint4*)(adjbits + ((long long)(g * 512 + ri)) * 16 + lane * 4);
        bitsW[wave][lane * 4 + 0] = v.x; bitsW[wave][lane * 4 + 1] = v.y;
        bitsW[wave][lane * 4 + 2] = v.z; bitsW[wave][lane * 4 + 3] = v.w;
    }
    __syncthreads();
    float asi = as_[g * K1 + i];
    float vals[4];
    float m = -1e30f;
#pragma unroll
    for (int e = 0; e < 4; ++e) {
        int j = e * 64 + lane;
        float x = asi + adL[j];
        x = (x >= 0.f) ? x : 0.2f * x;
        int jj = idxL[j];
        unsigned bit = (bitsW[wave][jj >> 5] >> (jj & 31)) & 1u;
        x += (float)bit;                    // LAMB = 1.0, adj exactly 0/1
        vals[e] = x; m = fmaxf(m, x);
    }
    m = wredmax(m);
    float S = 0.f;
#pragma unroll
    for (int e = 0; e < 4; ++e) { vals[e] = expf(vals[e] - m); S += vals[e]; }
    S = wredsum(S);
    float inv = 1.f / S, rs = 0.f;
    float* orow = a1 + ((long long)g * K1 + i) * K1;
#pragma unroll
    for (int e = 0; e < 4; ++e) {
        float p = vals[e] * inv; rs += p;
        orow[e * 64 + lane] = p;
        rowL[wave][e * 64 + lane] = p;
    }
    rs = wredsum(rs);
    if (lane == 0) { dgo[g * K1 + i] = rsqrtf(rs + 1.f); dio[g * K1 + i] = 1.f / fmaxf(rs, 1.f); }
    long long sb = ((long long)g * K1 + i) * K1 + lane * 4;
    ush hb[4], mb[4], lb[4];
#pragma unroll
    for (int q = 0; q < 4; ++q) split3(rowL[wave][lane * 4 + q], hb[q], mb[q], lb[q]);
    *(ushort4*)(Ahi  + sb) = make_ushort4(hb[0], hb[1], hb[2], hb[3]);
    *(ushort4*)(Amid + sb) = make_ushort4(mb[0], mb[1], mb[2], mb[3]);
    *(ushort4*)(Alo  + sb) = make_ushort4(lb[0], lb[1], lb[2], lb[3]);
}

// ---------------------------------------------------------------------------
// attention stage-2 (dense fp32 a1 source): writes a2 splits + deg
// ---------------------------------------------------------------------------
__global__ __launch_bounds__(256) void k_attn2(const float* __restrict__ a1,
        const int* __restrict__ idx, const float* __restrict__ as_, const float* __restrict__ ad_,
        ush* __restrict__ Ahi, ush* __restrict__ Amid, ush* __restrict__ Alo,
        float* __restrict__ dgo) {
    __shared__ int   idxL[K2];
    __shared__ float adL[K2];
    __shared__ float rowL[4][K1];
    int g = blockIdx.x / (K2 / 4);
    int wave = threadIdx.x >> 6, lane = threadIdx.x & 63;
    int i = (blockIdx.x % (K2 / 4)) * 4 + wave;
    for (int t = threadIdx.x; t < K2; t += 256) { idxL[t] = idx[g * K2 + t]; adL[t] = ad_[g * K2 + t]; }
    __syncthreads();
    int ri = idxL[i];
    const float* arow = a1 + ((long long)g * K1 + ri) * K1;
    for (int c = lane; c < K1; c += 64) rowL[wave][c] = arow[c];
    float asi = as_[g * K2 + i];
    float vals[2];
    float m = -1e30f;
#pragma unroll
    for (int e = 0; e < 2; ++e) {
        int j = e * 64 + lane;
        float x = asi + adL[j];
        x = (x >= 0.f) ? x : 0.2f * x;
        x += rowL[wave][idxL[j]];
        vals[e] = x; m = fmaxf(m, x);
    }
    m = wredmax(m);
    float S = 0.f;
#pragma unroll
    for (int e = 0; e < 2; ++e) { vals[e] = expf(vals[e] - m); S += vals[e]; }
    S = wredsum(S);
    float inv = 1.f / S, rs = 0.f;
#pragma unroll
    for (int e = 0; e < 2; ++e) {
        float p = vals[e] * inv; rs += p;
        rowL[wave][e * 64 + lane] = p;
    }
    rs = wredsum(rs);
    if (lane == 0) dgo[g * K2 + i] = rsqrtf(rs + 1.f);
    long long sb = ((long long)g * K2 + i) * K2 + lane * 2;
    ush hb[2], mb[2], lb[2];
#pragma unroll
    for (int q = 0; q < 2; ++q) split3(rowL[wave][lane * 2 + q], hb[q], mb[q], lb[q]);
    *(ushort2*)(Ahi  + sb) = make_ushort2(hb[0], hb[1]);
    *(ushort2*)(Amid + sb) = make_ushort2(mb[0], mb[1]);
    *(ushort2*)(Alo  + sb) = make_ushort2(lb[0], lb[1]);
}

// ---------------------------------------------------------------------------
// readout: [max over rows, mean over rows] -> (G, 256)
// ---------------------------------------------------------------------------
template<int KK>
__global__ __launch_bounds__(128) void k_readout(const float* __restrict__ xk, float* __restrict__ xo) {
    int g = blockIdx.x, f = threadIdx.x;
    const float* p = xk + (long long)g * KK * 128 + f;
    float m = -1e30f, s = 0.f;
    for (int r = 0; r < KK; ++r) { float v = p[r * 128]; m = fmaxf(m, v); s += v; }
    xo[g * 256 + f] = m;
    xo[g * 256 + 128 + f] = s * (1.0f / KK);
}

// ---------------------------------------------------------------------------
// final MLP + softmax, one block per graph
// ---------------------------------------------------------------------------
__global__ __launch_bounds__(128) void k_mlp(const float* __restrict__ x1, const float* __restrict__ x2,
        const float* __restrict__ x3,
        const float* __restrict__ Wl1, const float* __restrict__ bl1,
        const float* __restrict__ Wl2, const float* __restrict__ bl2,
        const float* __restrict__ Wl3, const float* __restrict__ bl3,
        float* __restrict__ out) {
    __shared__ float z[256], z1[128], z2[64], lg[10];
    int g = blockIdx.x, t = threadIdx.x;
    for (int k = t; k < 256; k += 128)
        z[k] = fmaxf(x1[g * 256 + k], 0.f) + fmaxf(x2[g * 256 + k], 0.f) + fmaxf(x3[g * 256 + k], 0.f);
    __syncthreads();
    {
        float acc = bl1[t];
        for (int k = 0; k < 256; ++k) acc = fmaf(z[k], Wl1[k * 128 + t], acc);
        z1[t] = fmaxf(acc, 0.f);
    }
    __syncthreads();
    if (t < 64) {
        float acc = bl2[t];
        for (int k = 0; k < 128; ++k) acc = fmaf(z1[k], Wl2[k * 64 + t], acc);
        z2[t] = fmaxf(acc, 0.f);
    }
    __syncthreads();
    if (t < 10) {
        float acc = bl3[t];
        for (int k = 0; k < 64; ++k) acc = fmaf(z2[k], Wl3[k * 10 + t], acc);
        lg[t] = acc;
    }
    __syncthreads();
    if (t == 0) {
        float m = -1e30f;
        for (int c = 0; c < 10; ++c) m = fmaxf(m, lg[c]);
        float S = 0.f;
        float e[10];
        for (int c = 0; c < 10; ++c) { e[c] = expf(lg[c] - m); S += e[c]; }
        float inv = 1.f / S;
        for (int c = 0; c < 10; ++c) out[g * 10 + c] = e[c] * inv;
    }
}

// ---------------------------------------------------------------------------
extern "C" void kernel_launch(void* const* d_in, const int* in_sizes, int n_in,
                              void* d_out, int out_size, void* d_ws, size_t ws_size,
                              hipStream_t stream) {
    const float* x     = (const float*)d_in[0];
    const float* adj   = (const float*)d_in[1];
    const float* W1    = (const float*)d_in[2];
    const float* b1    = (const float*)d_in[3];
    const float* W2    = (const float*)d_in[4];
    const float* b2    = (const float*)d_in[5];
    const float* W3    = (const float*)d_in[6];
    const float* b3    = (const float*)d_in[7];
    const float* att1s = (const float*)d_in[8];
    const float* att1d = (const float*)d_in[9];
    const float* att2s = (const float*)d_in[10];
    const float* att2d = (const float*)d_in[11];
    const float* Wl1   = (const float*)d_in[12];
    const float* bl1   = (const float*)d_in[13];
    const float* Wl2   = (const float*)d_in[14];
    const float* bl2   = (const float*)d_in[15];
    const float* Wl3   = (const float*)d_in[16];
    const float* bl3   = (const float*)d_in[17];
    float* out = (float*)d_out;

    char* ws = (char*)d_ws;
    // ---- workspace (~376 MB, no aliasing) ----
    unsigned* adjbits = (unsigned*)(ws + 0);        // 4,194,304
    ush*   T1hi   = (ush*)  (ws + 4194304);         // dxw1^T splits
    ush*   T1mid  = (ush*)  (ws + 20971520);
    ush*   T1lo   = (ush*)  (ws + 37748736);
    ush*   T2hi   = (ush*)  (ws + 54525952);        // h1^T splits
    ush*   T2mid  = (ush*)  (ws + 71303168);
    ush*   T2lo   = (ush*)  (ws + 88080384);
    float* dxw1   = (float*)(ws + 104857600);       // h1 in-place
    float* h1     = dxw1;
    float* a1     = (float*)(ws + 138412032);
    ush*   A1hi   = (ush*)  (ws + 171966464);       // a1 row-major splits
    ush*   A1mid  = (ush*)  (ws + 188743680);
    ush*   A1lo   = (ush*)  (ws + 205520896);
    float* xk1    = (float*)(ws + 222298112);
    float* dxw2   = (float*)(ws + 239075328);
    ush*   Y2hi   = (ush*)  (ws + 255852544);       // dxw2^T splits
    ush*   Y2mid  = (ush*)  (ws + 264241152);
    ush*   Y2lo   = (ush*)  (ws + 272629760);
    float* h2     = (float*)(ws + 281018368);
    ush*   H2hi   = (ush*)  (ws + 297795584);       // h2^T splits
    ush*   H2mid  = (ush*)  (ws + 306184192);
    ush*   H2lo   = (ush*)  (ws + 314572800);
    float* xk2    = (float*)(ws + 322961408);
    ush*   A2hi   = (ush*)  (ws + 331350016);       // a2 row-major splits
    ush*   A2mid  = (ush*)  (ws + 335544320);
    ush*   A2lo   = (ush*)  (ws + 339738624);
    float* dxw3   = (float*)(ws + 343932928);
    ush*   Y3hi   = (ush*)  (ws + 352321536);       // dxw3^T splits
    ush*   Y3mid  = (ush*)  (ws + 356515840);
    ush*   Y3lo   = (ush*)  (ws + 360710144);
    float* h3     = (float*)(ws + 364904448);
    float* s1     = (float*)(ws + 373293056);
    int*   idx1   = (int*)  (ws + 373555200);
    float* as1    = (float*)(ws + 373817344);
    float* ad1    = (float*)(ws + 373948416);
    float* dinv_g1= (float*)(ws + 374079488);
    float* dinv_i1= (float*)(ws + 374341632);
    float* dinv_g2= (float*)(ws + 374603776);
    float* dinv_i2= (float*)(ws + 374734848);
    float* x1r    = (float*)(ws + 374865920);
    float* s2     = (float*)(ws + 374996992);
    int*   idx2   = (int*)  (ws + 375128064);
    float* as2    = (float*)(ws + 375193600);
    float* ad2    = (float*)(ws + 375259136);
    float* dinv_g3= (float*)(ws + 375324672);
    float* x2r    = (float*)(ws + 375390208);
    float* x3r    = (float*)(ws + 375521280);

    // stage 1: full graph (N=512), bit-A pipelined MFMA aggregations
    k_prep<<<Gg * N1 / 4, 256, 0, stream>>>(adj, dinv_g1, dinv_i1, adjbits);
    k_gemm_rw<<<Gg * N1 / 64, 256, 0, stream>>>(x, W1, dxw1, dinv_g1);
    k_tsplit<N1><<<Gg * 16, 256, 0, stream>>>(dxw1, T1hi, T1mid, T1lo);
    k_aggb<0><<<Gg * 8, 256, 0, stream>>>(adjbits, T1hi, T1mid, T1lo, dinv_g1, dxw1, b1, h1, nullptr);
    k_tsplit<N1><<<Gg * 16, 256, 0, stream>>>(h1, T2hi, T2mid, T2lo);
    k_aggb<1><<<Gg * 8, 256, 0, stream>>>(adjbits, T2hi, T2mid, T2lo, dinv_i1, h1, nullptr, nullptr, s1);
    k_topk<N1, K1><<<Gg, 256, 0, stream>>>(s1, idx1);
    k_gather<K1><<<Gg * K1 / 4, 256, 0, stream>>>(h1, N1, idx1, att1s, att1d, xk1, as1, ad1);
    k_readout<K1><<<Gg, 128, 0, stream>>>(xk1, x1r);
    k_attn1b<<<Gg * K1 / 4, 256, 0, stream>>>(adjbits, idx1, as1, ad1, a1, A1hi, A1mid, A1lo,
                                              dinv_g2, dinv_i2);

    // stage 2: pooled graph (K1=256), split-A pipelined MFMA
    k_gemm_rw<<<Gg * K1 / 64, 256, 0, stream>>>(xk1, W2, dxw2, dinv_g2);
    k_tsplit<K1><<<Gg * 8, 256, 0, stream>>>(dxw2, Y2hi, Y2mid, Y2lo);
    k_aggs<K1, 0><<<Gg * 4, 256, 0, stream>>>(A1hi, A1mid, A1lo, Y2hi, Y2mid, Y2lo,
                                              dinv_g2, dxw2, b2, h2, nullptr);
    k_tsplit<K1><<<Gg * 8, 256, 0, stream>>>(h2, H2hi, H2mid, H2lo);
    k_aggs<K1, 1><<<Gg * 4, 256, 0, stream>>>(A1hi, A1mid, A1lo, H2hi, H2mid, H2lo,
                                              dinv_i2, h2, nullptr, nullptr, s2);
    k_topk<K1, K2><<<Gg, 256, 0, stream>>>(s2, idx2);
    k_gather<K2><<<Gg * K2 / 4, 256, 0, stream>>>(h2, K1, idx2, att2s, att2d, xk2, as2, ad2);
    k_readout<K2><<<Gg, 128, 0, stream>>>(xk2, x2r);
    k_attn2<<<Gg * K2 / 4, 256, 0, stream>>>(a1, idx2, as2, ad2, A2hi, A2mid, A2lo, dinv_g3);

    // stage 3: pooled graph (K2=128)
    k_gemm_rw<<<Gg * K2 / 64, 256, 0, stream>>>(xk2, W3, dxw3, dinv_g3);
    k_tsplit<K2><<<Gg * 4, 256, 0, stream>>>(dxw3, Y3hi, Y3mid, Y3lo);
    k_aggs<K2, 0><<<Gg * 2, 256, 0, stream>>>(A2hi, A2mid, A2lo, Y3hi, Y3mid, Y3lo,
                                              dinv_g3, dxw3, b3, h3, nullptr);
    k_readout<K2><<<Gg, 128, 0, stream>>>(h3, x3r);

    // final MLP
    k_mlp<<<Gg, 128, 0, stream>>>(x1r, x2r, x3r, Wl1, bl1, Wl2, bl2, Wl3, bl3, out);
}

// Round 7
// 652.019 us; speedup vs baseline: 1.1296x; 1.1296x over previous
//
#include <hip/hip_runtime.h>

// Sizes
#define Gg   128
#define N1   512
#define FH   128
#define K1   256
#define K2   128

typedef unsigned short ush;
typedef __bf16 bf16x8 __attribute__((ext_vector_type(8)));
typedef float  floatx4 __attribute__((ext_vector_type(4)));

__device__ inline float wredsum(float v) {
#pragma unroll
    for (int o = 32; o; o >>= 1) v += __shfl_xor(v, o, 64);
    return v;
}
__device__ inline float wredmax(float v) {
#pragma unroll
    for (int o = 32; o; o >>= 1) v = fmaxf(v, __shfl_xor(v, o, 64));
    return v;
}
__device__ inline ush bf_rne(float x) {
    unsigned u = __float_as_uint(x);
    return (ush)((u + 0x7fffu + ((u >> 16) & 1u)) >> 16);
}
__device__ inline float bf2f(ush u) { return __uint_as_float((unsigned)u << 16); }
__device__ inline void split3(float v, ush& h, ush& m, ush& l) {
    h = bf_rne(v);
    float r1 = v - bf2f(h);
    m = bf_rne(r1);
    l = bf_rne(r1 - bf2f(m));
}
__device__ __forceinline__ bf16x8 expand_bits(unsigned word, int quad) {
    unsigned byte = (word >> (quad * 8)) & 0xffu;
    unsigned au[4] __attribute__((aligned(16)));
    au[0] = ((byte & 1u)   ? 0x3F80u : 0u) | ((byte & 2u)   ? 0x3F800000u : 0u);
    au[1] = ((byte & 4u)   ? 0x3F80u : 0u) | ((byte & 8u)   ? 0x3F800000u : 0u);
    au[2] = ((byte & 16u)  ? 0x3F80u : 0u) | ((byte & 32u)  ? 0x3F800000u : 0u);
    au[3] = ((byte & 64u)  ? 0x3F80u : 0u) | ((byte & 128u) ? 0x3F800000u : 0u);
    return *(const bf16x8*)au;
}

// ---------------------------------------------------------------------------
// prep: degrees + 1-bit packed adjacency (adj values exactly 0/1)
// ---------------------------------------------------------------------------
__global__ __launch_bounds__(256) void k_prep(const float* __restrict__ adj,
        float* __restrict__ dinv_gcn, float* __restrict__ dinv_info,
        unsigned* __restrict__ adjbits) {
    int wave = threadIdx.x >> 6, lane = threadIdx.x & 63;
    long long row = (long long)blockIdx.x * 4 + wave;
    const float* ar = adj + row * N1;
    float s = 0.f;
    unsigned myw = 0;
#pragma unroll
    for (int c = 0; c < 8; ++c) {
        float v = ar[c * 64 + lane];
        s += v;
        unsigned long long mk = __ballot(v != 0.0f);
        unsigned lo = (unsigned)mk, hi = (unsigned)(mk >> 32);
        if ((lane >> 1) == c) myw = (lane & 1) ? hi : lo;
    }
    if (lane < 16) adjbits[row * 16 + lane] = myw;
    s = wredsum(s);
    if (lane == 0) {
        dinv_gcn[row]  = rsqrtf(s + 1.0f);
        dinv_info[row] = 1.0f / fmaxf(s, 1.0f);
    }
}

// ---------------------------------------------------------------------------
// Row-weight GEMM: C[M,128] = rs[row] * (A[M,128] @ W[128,128])  (rs optional)
// ---------------------------------------------------------------------------
__global__ __launch_bounds__(256) void k_gemm_rw(const float* __restrict__ A,
        const float* __restrict__ W, float* __restrict__ C,
        const float* __restrict__ rs) {
    __shared__ float Al[64][68];
    __shared__ float Wl[64][132];
    long long row0 = (long long)blockIdx.x * 64;
    int tid = threadIdx.x, tr = tid >> 4, tc = tid & 15;
    float acc[4][8] = {};
    for (int ch = 0; ch < 2; ++ch) {
        for (int p = tid; p < 1024; p += 256) {
            int r = p >> 4, c4 = p & 15;
            *(float4*)&Al[r][c4 * 4] = *(const float4*)(A + (row0 + r) * 128 + ch * 64 + c4 * 4);
        }
        for (int p = tid; p < 2048; p += 256) {
            int r = p >> 5, c4 = p & 31;
            *(float4*)&Wl[r][c4 * 4] = *(const float4*)(W + (ch * 64 + r) * 128 + c4 * 4);
        }
        __syncthreads();
        for (int k = 0; k < 64; ++k) {
            float4 w0 = *(const float4*)&Wl[k][tc * 8];
            float4 w1 = *(const float4*)&Wl[k][tc * 8 + 4];
            float w[8] = {w0.x, w0.y, w0.z, w0.w, w1.x, w1.y, w1.z, w1.w};
#pragma unroll
            for (int i = 0; i < 4; ++i) {
                float a = Al[tr * 4 + i][k];
#pragma unroll
                for (int j = 0; j < 8; ++j) acc[i][j] = fmaf(a, w[j], acc[i][j]);
            }
        }
        __syncthreads();
    }
#pragma unroll
    for (int i = 0; i < 4; ++i) {
        long long r = row0 + tr * 4 + i;
        float sc = rs ? rs[r] : 1.0f;
        *(float4*)(C + r * 128 + tc * 8)     = make_float4(sc * acc[i][0], sc * acc[i][1], sc * acc[i][2], sc * acc[i][3]);
        *(float4*)(C + r * 128 + tc * 8 + 4) = make_float4(sc * acc[i][4], sc * acc[i][5], sc * acc[i][6], sc * acc[i][7]);
    }
}

// ---------------------------------------------------------------------------
// transpose + 3-way bf16 split: feat[g*KD][128] fp32 -> T{hi,mid,lo}[g][128][KD]
// ---------------------------------------------------------------------------
template<int KD>
__global__ __launch_bounds__(256) void k_tsplit(const float* __restrict__ feat,
        ush* __restrict__ Thi, ush* __restrict__ Tmid, ush* __restrict__ Tlo) {
    __shared__ float tile[64 * 65];
    int b = blockIdx.x;                    // (G*KD/64) * 2
    int cb = b & 1;
    long long row0 = (long long)(b >> 1) * 64;
    int g = (int)(row0 / KD);
    int rk0 = (int)(row0 % KD);
    int t = threadIdx.x;
    {
        int r0 = t >> 4, c4 = t & 15;
#pragma unroll
        for (int i = 0; i < 4; ++i) {
            int r = r0 + i * 16;
            float4 v = *(const float4*)(feat + (row0 + r) * 128 + cb * 64 + c4 * 4);
            tile[r * 65 + c4 * 4 + 0] = v.x;
            tile[r * 65 + c4 * 4 + 1] = v.y;
            tile[r * 65 + c4 * 4 + 2] = v.z;
            tile[r * 65 + c4 * 4 + 3] = v.w;
        }
    }
    __syncthreads();
    int tf = t >> 2, chunk = t & 3;
    ush hbuf[16] __attribute__((aligned(16)));
    ush mbuf[16] __attribute__((aligned(16)));
    ush lbuf[16] __attribute__((aligned(16)));
#pragma unroll
    for (int i = 0; i < 16; ++i) {
        int m = chunk * 16 + i;
        split3(tile[m * 65 + tf], hbuf[i], mbuf[i], lbuf[i]);
    }
    long long obase = ((long long)g * 128 + cb * 64 + tf) * KD + rk0 + chunk * 16;
    *(uint4*)(Thi + obase)      = *(const uint4*)&hbuf[0];
    *(uint4*)(Thi + obase + 8)  = *(const uint4*)&hbuf[8];
    *(uint4*)(Tmid + obase)     = *(const uint4*)&mbuf[0];
    *(uint4*)(Tmid + obase + 8) = *(const uint4*)&mbuf[8];
    *(uint4*)(Tlo + obase)      = *(const uint4*)&lbuf[0];
    *(uint4*)(Tlo + obase + 8)  = *(const uint4*)&lbuf[8];
}

// ---------------------------------------------------------------------------
// TRANSPOSED bit-B MFMA aggregation (stage 1, adj symmetric):
//   C'[f][i] = sum_j featT[f][j] * adj[j][i]   (A = featT splits, B = bits)
// Block: f 128 x i 128, 4 waves (2x2 of 64x64); 4 i-blocks/graph -> 512 blocks.
// B expanded from LDS bits (no loads); A per-lane 16B loads (full-line coalesced).
//  EPI 0: h[i][f] = relu(di[i]*(C'+hx[i][f]) + bias[f])  (in-place over hx ok)
//  EPI 1: outS[i] = sum_f |hx[i][f] - C'*di[i]|
// ---------------------------------------------------------------------------
template<int EPI>
__global__ __launch_bounds__(256) void k_aggbT(const unsigned* __restrict__ adjbits,
        const ush* __restrict__ Ahi, const ush* __restrict__ Amid, const ush* __restrict__ Alo,
        const float* __restrict__ dvec, const float* __restrict__ hx,
        const float* __restrict__ bias, float* __restrict__ outH, float* __restrict__ outS) {
    __shared__ unsigned bitsL[128 * 17];
    __shared__ float sred[2][128];
    int b = blockIdx.x;                        // 512
    int g  = (b & 7) + ((b >> 5) << 3);        // 4 i-blocks of graph g share an XCD
    int ib = (b >> 3) & 3;
    int tid = threadIdx.x;
    int w = tid >> 6, lane = tid & 63;
    int wm = w >> 1, wn = w & 1;               // wm: f-half, wn: i-half
    int ln = lane & 15, quad = lane >> 4;
    {   // stage bits for this block's 128 i-rows (8.5 KB)
        int r = tid >> 1, w8 = (tid & 1) * 8;
        const unsigned* src = adjbits + ((long long)(g * 512 + ib * 128 + r)) * 16 + w8;
        uint4 v0 = *(const uint4*)src;
        uint4 v1 = *(const uint4*)(src + 4);
        unsigned* dst = &bitsL[r * 17 + w8];
        dst[0] = v0.x; dst[1] = v0.y; dst[2] = v0.z; dst[3] = v0.w;
        dst[4] = v1.x; dst[5] = v1.y; dst[6] = v1.z; dst[7] = v1.w;
    }
    __syncthreads();
    floatx4 acc[4][4];
#pragma unroll
    for (int i = 0; i < 4; ++i)
#pragma unroll
        for (int j = 0; j < 4; ++j) { floatx4 z = {0.f, 0.f, 0.f, 0.f}; acc[i][j] = z; }

    long long aoff[4];
#pragma unroll
    for (int tm = 0; tm < 4; ++tm)
        aoff[tm] = ((long long)g * 128 + wm * 64 + tm * 16 + ln) * 512 + quad * 8;
    int boffL[4];
#pragma unroll
    for (int tn = 0; tn < 4; ++tn)
        boffL[tn] = (wn * 64 + tn * 16 + ln) * 17;

#pragma unroll 2
    for (int kt = 0; kt < 16; ++kt) {
        int kk = kt * 32;
        bf16x8 ah[4], am[4], al[4];
#pragma unroll
        for (int tm = 0; tm < 4; ++tm) {
            ah[tm] = *(const bf16x8*)(Ahi  + aoff[tm] + kk);
            am[tm] = *(const bf16x8*)(Amid + aoff[tm] + kk);
            al[tm] = *(const bf16x8*)(Alo  + aoff[tm] + kk);
        }
#pragma unroll
        for (int tn = 0; tn < 4; ++tn) {
            bf16x8 bb = expand_bits(bitsL[boffL[tn] + kt], quad);
#pragma unroll
            for (int tm = 0; tm < 4; ++tm) {
                acc[tm][tn] = __builtin_amdgcn_mfma_f32_16x16x32_bf16(ah[tm], bb, acc[tm][tn], 0, 0, 0);
                acc[tm][tn] = __builtin_amdgcn_mfma_f32_16x16x32_bf16(am[tm], bb, acc[tm][tn], 0, 0, 0);
                acc[tm][tn] = __builtin_amdgcn_mfma_f32_16x16x32_bf16(al[tm], bb, acc[tm][tn], 0, 0, 0);
            }
        }
    }
    // epilogue: D[m=f][n=i]; row = quad*4+r (f), col = ln (i)
    if (EPI == 0) {
#pragma unroll
        for (int tn = 0; tn < 4; ++tn) {
            long long grow = (long long)g * 512 + ib * 128 + wn * 64 + tn * 16 + ln;
            float di = dvec[grow];
#pragma unroll
            for (int tm = 0; tm < 4; ++tm) {
                int f0 = wm * 64 + tm * 16 + quad * 4;
                float4 hv = *(const float4*)(hx + grow * 128 + f0);
                float4 bv = *(const float4*)(bias + f0);
                float4 o;
                o.x = fmaxf(fmaf(di, acc[tm][tn][0] + hv.x, bv.x), 0.f);
                o.y = fmaxf(fmaf(di, acc[tm][tn][1] + hv.y, bv.y), 0.f);
                o.z = fmaxf(fmaf(di, acc[tm][tn][2] + hv.z, bv.z), 0.f);
                o.w = fmaxf(fmaf(di, acc[tm][tn][3] + hv.w, bv.w), 0.f);
                *(float4*)(outH + grow * 128 + f0) = o;
            }
        }
    } else {
#pragma unroll
        for (int tn = 0; tn < 4; ++tn) {
            int il = wn * 64 + tn * 16 + ln;
            long long grow = (long long)g * 512 + ib * 128 + il;
            float di = dvec[grow];
            float p = 0.f;
#pragma unroll
            for (int tm = 0; tm < 4; ++tm) {
                int f0 = wm * 64 + tm * 16 + quad * 4;
                float4 hv = *(const float4*)(hx + grow * 128 + f0);
                p += fabsf(hv.x - acc[tm][tn][0] * di) + fabsf(hv.y - acc[tm][tn][1] * di)
                   + fabsf(hv.z - acc[tm][tn][2] * di) + fabsf(hv.w - acc[tm][tn][3] * di);
            }
            p += __shfl_xor(p, 16); p += __shfl_xor(p, 32);   // reduce over quads
            if (quad == 0) sred[wm][il] = p;
        }
        __syncthreads();
        if (tid < 128)
            outS[(long long)g * 512 + ib * 128 + tid] = sred[0][tid] + sred[1][tid];
    }
}

// ---------------------------------------------------------------------------
// TRANSPOSED split-A x split-B MFMA aggregation (stages 2/3):
//   C'[f][i] = sum_j YT[f][j] * P[i][j]  (A = YT feature splits k-major,
//   B = attention row-major splits — exactly the B[n][k] layout)
// Block: f (TM*32) x i 128; 6 cross-term MFMAs (~fp32 accuracy).
// ---------------------------------------------------------------------------
template<int KD, int TM, int EPI>
__global__ __launch_bounds__(256) void k_aggsT(
        const ush* __restrict__ Fhi, const ush* __restrict__ Fmid, const ush* __restrict__ Flo,
        const ush* __restrict__ Phi, const ush* __restrict__ Pmid, const ush* __restrict__ Plo,
        const float* __restrict__ dvec, const float* __restrict__ hx,
        const float* __restrict__ bias, float* __restrict__ outH, float* __restrict__ outS) {
    __shared__ float sred[2][128];
    constexpr int FB = TM * 32;                // block f-extent
    constexpr int bpgF = 128 / FB;
    constexpr int bpgI = KD / 128;
    constexpr int BPG = bpgF * bpgI;
    int b = blockIdx.x;                        // Gg * BPG
    int g   = (b & 7) + ((b / (8 * BPG)) << 3);
    int sub = (b >> 3) % BPG;
    int fb = sub / bpgI, ib2 = sub % bpgI;
    int tid = threadIdx.x;
    int w = tid >> 6, lane = tid & 63;
    int wm = w >> 1, wn = w & 1;
    int ln = lane & 15, quad = lane >> 4;
    floatx4 acc[TM][4];
#pragma unroll
    for (int i = 0; i < TM; ++i)
#pragma unroll
        for (int j = 0; j < 4; ++j) { floatx4 z = {0.f, 0.f, 0.f, 0.f}; acc[i][j] = z; }

    long long aoff[TM], boff[4];
#pragma unroll
    for (int tm = 0; tm < TM; ++tm)
        aoff[tm] = ((long long)g * 128 + fb * FB + wm * (FB / 2) + tm * 16 + ln) * KD + quad * 8;
#pragma unroll
    for (int tn = 0; tn < 4; ++tn)
        boff[tn] = ((long long)g * KD + ib2 * 128 + wn * 64 + tn * 16 + ln) * KD + quad * 8;

#pragma unroll 2
    for (int kt = 0; kt < KD / 32; ++kt) {
        int kk = kt * 32;
        bf16x8 ah[TM], am[TM], al[TM];
#pragma unroll
        for (int tm = 0; tm < TM; ++tm) {
            ah[tm] = *(const bf16x8*)(Fhi  + aoff[tm] + kk);
            am[tm] = *(const bf16x8*)(Fmid + aoff[tm] + kk);
            al[tm] = *(const bf16x8*)(Flo  + aoff[tm] + kk);
        }
#pragma unroll
        for (int tn = 0; tn < 4; ++tn) {
            bf16x8 bh = *(const bf16x8*)(Phi  + boff[tn] + kk);
            bf16x8 bm = *(const bf16x8*)(Pmid + boff[tn] + kk);
            bf16x8 bl = *(const bf16x8*)(Plo  + boff[tn] + kk);
#pragma unroll
            for (int tm = 0; tm < TM; ++tm) {
                floatx4 a = acc[tm][tn];
                a = __builtin_amdgcn_mfma_f32_16x16x32_bf16(ah[tm], bh, a, 0, 0, 0);
                a = __builtin_amdgcn_mfma_f32_16x16x32_bf16(ah[tm], bm, a, 0, 0, 0);
                a = __builtin_amdgcn_mfma_f32_16x16x32_bf16(am[tm], bh, a, 0, 0, 0);
                a = __builtin_amdgcn_mfma_f32_16x16x32_bf16(ah[tm], bl, a, 0, 0, 0);
                a = __builtin_amdgcn_mfma_f32_16x16x32_bf16(al[tm], bh, a, 0, 0, 0);
                a = __builtin_amdgcn_mfma_f32_16x16x32_bf16(am[tm], bm, a, 0, 0, 0);
                acc[tm][tn] = a;
            }
        }
    }
    if (EPI == 0) {
#pragma unroll
        for (int tn = 0; tn < 4; ++tn) {
            long long grow = (long long)g * KD + ib2 * 128 + wn * 64 + tn * 16 + ln;
            float di = dvec[grow];
#pragma unroll
            for (int tm = 0; tm < TM; ++tm) {
                int f0 = fb * FB + wm * (FB / 2) + tm * 16 + quad * 4;
                float4 hv = *(const float4*)(hx + grow * 128 + f0);
                float4 bv = *(const float4*)(bias + f0);
                float4 o;
                o.x = fmaxf(fmaf(di, acc[tm][tn][0] + hv.x, bv.x), 0.f);
                o.y = fmaxf(fmaf(di, acc[tm][tn][1] + hv.y, bv.y), 0.f);
                o.z = fmaxf(fmaf(di, acc[tm][tn][2] + hv.z, bv.z), 0.f);
                o.w = fmaxf(fmaf(di, acc[tm][tn][3] + hv.w, bv.w), 0.f);
                *(float4*)(outH + grow * 128 + f0) = o;
            }
        }
    } else {   // only instantiated with TM=4 (block covers all 128 f)
#pragma unroll
        for (int tn = 0; tn < 4; ++tn) {
            int il = wn * 64 + tn * 16 + ln;
            long long grow = (long long)g * KD + ib2 * 128 + il;
            float di = dvec[grow];
            float p = 0.f;
#pragma unroll
            for (int tm = 0; tm < TM; ++tm) {
                int f0 = fb * FB + wm * (FB / 2) + tm * 16 + quad * 4;
                float4 hv = *(const float4*)(hx + grow * 128 + f0);
                p += fabsf(hv.x - acc[tm][tn][0] * di) + fabsf(hv.y - acc[tm][tn][1] * di)
                   + fabsf(hv.z - acc[tm][tn][2] * di) + fabsf(hv.w - acc[tm][tn][3] * di);
            }
            p += __shfl_xor(p, 16); p += __shfl_xor(p, 32);
            if (quad == 0) sred[wm][il] = p;
        }
        __syncthreads();
        if (tid < 128)
            outS[(long long)g * KD + ib2 * 128 + tid] = sred[0][tid] + sred[1][tid];
    }
}

// ---------------------------------------------------------------------------
// top-k: bitonic sort of packed keys -> value desc, index asc (jax.lax.top_k)
// ---------------------------------------------------------------------------
template<int NT, int KSEL>
__global__ __launch_bounds__(256) void k_topk(const float* __restrict__ s, int* __restrict__ idx) {
    __shared__ unsigned long long keys[NT];
    int g = blockIdx.x;
    const float* sg = s + g * NT;
    for (int t = threadIdx.x; t < NT; t += 256) {
        unsigned int b = __float_as_uint(sg[t]);
        unsigned int ord = (b & 0x80000000u) ? ~b : (b | 0x80000000u);
        keys[t] = ((unsigned long long)(~ord) << 32) | (unsigned int)t;
    }
    __syncthreads();
    for (int k = 2; k <= NT; k <<= 1) {
        for (int j = k >> 1; j > 0; j >>= 1) {
            for (int i = threadIdx.x; i < NT; i += 256) {
                int l = i ^ j;
                if (l > i) {
                    bool dir = ((i & k) == 0);
                    unsigned long long a = keys[i], b2 = keys[l];
                    bool sw = dir ? (a > b2) : (a < b2);
                    if (sw) { keys[i] = b2; keys[l] = a; }
                }
            }
            __syncthreads();
        }
    }
    for (int t = threadIdx.x; t < KSEL; t += 256)
        idx[g * KSEL + t] = (int)(keys[t] & 0xffffffffu);
}

// ---------------------------------------------------------------------------
// gather pooled rows + attention dot products
// ---------------------------------------------------------------------------
template<int KK>
__global__ __launch_bounds__(256) void k_gather(const float* __restrict__ h, int srcN,
        const int* __restrict__ idx, const float* __restrict__ atts, const float* __restrict__ attd,
        float* __restrict__ xk, float* __restrict__ as_, float* __restrict__ ad_) {
    int wave = threadIdx.x >> 6, lane = threadIdx.x & 63;
    int r = blockIdx.x * 4 + wave;
    int g = r / KK;
    int j = idx[r];
    float2 v = *(const float2*)(h + ((long long)g * srcN + j) * 128 + lane * 2);
    *(float2*)(xk + (long long)r * 128 + lane * 2) = v;
    float2 sv = *(const float2*)(atts + lane * 2);
    float2 dv = *(const float2*)(attd + lane * 2);
    float ps = v.x * sv.x + v.y * sv.y;
    float pd = v.x * dv.x + v.y * dv.y;
    ps = wredsum(ps); pd = wredsum(pd);
    if (lane == 0) { as_[r] = ps; ad_[r] = pd; }
}

// ---------------------------------------------------------------------------
// attention stage-1 (bit adjacency): softmax(leaky(as_i+ad_j)+bit) ->
// dense a1 + row-major 3-splits + deg epilogues
// ---------------------------------------------------------------------------
__global__ __launch_bounds__(256) void k_attn1b(const unsigned* __restrict__ adjbits,
        const int* __restrict__ idx, const float* __restrict__ as_, const float* __restrict__ ad_,
        float* __restrict__ a1, ush* __restrict__ Ahi, ush* __restrict__ Amid, ush* __restrict__ Alo,
        float* __restrict__ dgo, float* __restrict__ dio) {
    __shared__ int   idxL[K1];
    __shared__ float adL[K1];
    __shared__ unsigned bitsW[4][20];
    __shared__ float rowL[4][K1];
    int g = blockIdx.x / (K1 / 4);
    int wave = threadIdx.x >> 6, lane = threadIdx.x & 63;
    int i = (blockIdx.x % (K1 / 4)) * 4 + wave;
    for (int t = threadIdx.x; t < K1; t += 256) { idxL[t] = idx[g * K1 + t]; adL[t] = ad_[g * K1 + t]; }
    __syncthreads();
    int ri = idxL[i];
    if (lane < 4) {
        uint4 v = *(const uint4*)(adjbits + ((long long)(g * 512 + ri)) * 16 + lane * 4);
        bitsW[wave][lane * 4 + 0] = v.x; bitsW[wave][lane * 4 + 1] = v.y;
        bitsW[wave][lane * 4 + 2] = v.z; bitsW[wave][lane * 4 + 3] = v.w;
    }
    __syncthreads();
    float asi = as_[g * K1 + i];
    float vals[4];
    float m = -1e30f;
#pragma unroll
    for (int e = 0; e < 4; ++e) {
        int j = e * 64 + lane;
        float x = asi + adL[j];
        x = (x >= 0.f) ? x : 0.2f * x;
        int jj = idxL[j];
        unsigned bit = (bitsW[wave][jj >> 5] >> (jj & 31)) & 1u;
        x += (float)bit;                    // LAMB = 1.0, adj exactly 0/1
        vals[e] = x; m = fmaxf(m, x);
    }
    m = wredmax(m);
    float S = 0.f;
#pragma unroll
    for (int e = 0; e < 4; ++e) { vals[e] = expf(vals[e] - m); S += vals[e]; }
    S = wredsum(S);
    float inv = 1.f / S, rs = 0.f;
    float* orow = a1 + ((long long)g * K1 + i) * K1;
#pragma unroll
    for (int e = 0; e < 4; ++e) {
        float p = vals[e] * inv; rs += p;
        orow[e * 64 + lane] = p;
        rowL[wave][e * 64 + lane] = p;
    }
    rs = wredsum(rs);
    if (lane == 0) { dgo[g * K1 + i] = rsqrtf(rs + 1.f); dio[g * K1 + i] = 1.f / fmaxf(rs, 1.f); }
    long long sb = ((long long)g * K1 + i) * K1 + lane * 4;
    ush hb[4], mb[4], lb[4];
#pragma unroll
    for (int q = 0; q < 4; ++q) split3(rowL[wave][lane * 4 + q], hb[q], mb[q], lb[q]);
    *(ushort4*)(Ahi  + sb) = make_ushort4(hb[0], hb[1], hb[2], hb[3]);
    *(ushort4*)(Amid + sb) = make_ushort4(mb[0], mb[1], mb[2], mb[3]);
    *(ushort4*)(Alo  + sb) = make_ushort4(lb[0], lb[1], lb[2], lb[3]);
}

// ---------------------------------------------------------------------------
// attention stage-2 (dense fp32 a1 source): writes a2 splits + deg
// ---------------------------------------------------------------------------
__global__ __launch_bounds__(256) void k_attn2(const float* __restrict__ a1,
        const int* __restrict__ idx, const float* __restrict__ as_, const float* __restrict__ ad_,
        ush* __restrict__ Ahi, ush* __restrict__ Amid, ush* __restrict__ Alo,
        float* __restrict__ dgo) {
    __shared__ int   idxL[K2];
    __shared__ float adL[K2];
    __shared__ float rowL[4][K1];
    int g = blockIdx.x / (K2 / 4);
    int wave = threadIdx.x >> 6, lane = threadIdx.x & 63;
    int i = (blockIdx.x % (K2 / 4)) * 4 + wave;
    for (int t = threadIdx.x; t < K2; t += 256) { idxL[t] = idx[g * K2 + t]; adL[t] = ad_[g * K2 + t]; }
    __syncthreads();
    int ri = idxL[i];
    const float* arow = a1 + ((long long)g * K1 + ri) * K1;
    for (int c = lane; c < K1; c += 64) rowL[wave][c] = arow[c];
    float asi = as_[g * K2 + i];
    float vals[2];
    float m = -1e30f;
#pragma unroll
    for (int e = 0; e < 2; ++e) {
        int j = e * 64 + lane;
        float x = asi + adL[j];
        x = (x >= 0.f) ? x : 0.2f * x;
        x += rowL[wave][idxL[j]];
        vals[e] = x; m = fmaxf(m, x);
    }
    m = wredmax(m);
    float S = 0.f;
#pragma unroll
    for (int e = 0; e < 2; ++e) { vals[e] = expf(vals[e] - m); S += vals[e]; }
    S = wredsum(S);
    float inv = 1.f / S, rs = 0.f;
#pragma unroll
    for (int e = 0; e < 2; ++e) {
        float p = vals[e] * inv; rs += p;
        rowL[wave][e * 64 + lane] = p;
    }
    rs = wredsum(rs);
    if (lane == 0) dgo[g * K2 + i] = rsqrtf(rs + 1.f);
    long long sb = ((long long)g * K2 + i) * K2 + lane * 2;
    ush hb[2], mb[2], lb[2];
#pragma unroll
    for (int q = 0; q < 2; ++q) split3(rowL[wave][lane * 2 + q], hb[q], mb[q], lb[q]);
    *(ushort2*)(Ahi  + sb) = make_ushort2(hb[0], hb[1]);
    *(ushort2*)(Amid + sb) = make_ushort2(mb[0], mb[1]);
    *(ushort2*)(Alo  + sb) = make_ushort2(lb[0], lb[1]);
}

// ---------------------------------------------------------------------------
// readout: [max over rows, mean over rows] -> (G, 256)
// ---------------------------------------------------------------------------
template<int KK>
__global__ __launch_bounds__(128) void k_readout(const float* __restrict__ xk, float* __restrict__ xo) {
    int g = blockIdx.x, f = threadIdx.x;
    const float* p = xk + (long long)g * KK * 128 + f;
    float m = -1e30f, s = 0.f;
    for (int r = 0; r < KK; ++r) { float v = p[r * 128]; m = fmaxf(m, v); s += v; }
    xo[g * 256 + f] = m;
    xo[g * 256 + 128 + f] = s * (1.0f / KK);
}

// ---------------------------------------------------------------------------
// final MLP + softmax, one block per graph
// ---------------------------------------------------------------------------
__global__ __launch_bounds__(128) void k_mlp(const float* __restrict__ x1, const float* __restrict__ x2,
        const float* __restrict__ x3,
        const float* __restrict__ Wl1, const float* __restrict__ bl1,
        const float* __restrict__ Wl2, const float* __restrict__ bl2,
        const float* __restrict__ Wl3, const float* __restrict__ bl3,
        float* __restrict__ out) {
    __shared__ float z[256], z1[128], z2[64], lg[10];
    int g = blockIdx.x, t = threadIdx.x;
    for (int k = t; k < 256; k += 128)
        z[k] = fmaxf(x1[g * 256 + k], 0.f) + fmaxf(x2[g * 256 + k], 0.f) + fmaxf(x3[g * 256 + k], 0.f);
    __syncthreads();
    {
        float acc = bl1[t];
        for (int k = 0; k < 256; ++k) acc = fmaf(z[k], Wl1[k * 128 + t], acc);
        z1[t] = fmaxf(acc, 0.f);
    }
    __syncthreads();
    if (t < 64) {
        float acc = bl2[t];
        for (int k = 0; k < 128; ++k) acc = fmaf(z1[k], Wl2[k * 64 + t], acc);
        z2[t] = fmaxf(acc, 0.f);
    }
    __syncthreads();
    if (t < 10) {
        float acc = bl3[t];
        for (int k = 0; k < 64; ++k) acc = fmaf(z2[k], Wl3[k * 10 + t], acc);
        lg[t] = acc;
    }
    __syncthreads();
    if (t == 0) {
        float m = -1e30f;
        for (int c = 0; c < 10; ++c) m = fmaxf(m, lg[c]);
        float S = 0.f;
        float e[10];
        for (int c = 0; c < 10; ++c) { e[c] = expf(lg[c] - m); S += e[c]; }
        float inv = 1.f / S;
        for (int c = 0; c < 10; ++c) out[g * 10 + c] = e[c] * inv;
    }
}

// ---------------------------------------------------------------------------
extern "C" void kernel_launch(void* const* d_in, const int* in_sizes, int n_in,
                              void* d_out, int out_size, void* d_ws, size_t ws_size,
                              hipStream_t stream) {
    const float* x     = (const float*)d_in[0];
    const float* adj   = (const float*)d_in[1];
    const float* W1    = (const float*)d_in[2];
    const float* b1    = (const float*)d_in[3];
    const float* W2    = (const float*)d_in[4];
    const float* b2    = (const float*)d_in[5];
    const float* W3    = (const float*)d_in[6];
    const float* b3    = (const float*)d_in[7];
    const float* att1s = (const float*)d_in[8];
    const float* att1d = (const float*)d_in[9];
    const float* att2s = (const float*)d_in[10];
    const float* att2d = (const float*)d_in[11];
    const float* Wl1   = (const float*)d_in[12];
    const float* bl1   = (const float*)d_in[13];
    const float* Wl2   = (const float*)d_in[14];
    const float* bl2   = (const float*)d_in[15];
    const float* Wl3   = (const float*)d_in[16];
    const float* bl3   = (const float*)d_in[17];
    float* out = (float*)d_out;

    char* ws = (char*)d_ws;
    // ---- workspace (~376 MB, no aliasing) ----
    unsigned* adjbits = (unsigned*)(ws + 0);        // 4,194,304
    ush*   T1hi   = (ush*)  (ws + 4194304);         // dxw1^T splits
    ush*   T1mid  = (ush*)  (ws + 20971520);
    ush*   T1lo   = (ush*)  (ws + 37748736);
    ush*   T2hi   = (ush*)  (ws + 54525952);        // h1^T splits
    ush*   T2mid  = (ush*)  (ws + 71303168);
    ush*   T2lo   = (ush*)  (ws + 88080384);
    float* dxw1   = (float*)(ws + 104857600);       // h1 in-place
    float* h1     = dxw1;
    float* a1     = (float*)(ws + 138412032);
    ush*   A1hi   = (ush*)  (ws + 171966464);       // a1 row-major splits
    ush*   A1mid  = (ush*)  (ws + 188743680);
    ush*   A1lo   = (ush*)  (ws + 205520896);
    float* xk1    = (float*)(ws + 222298112);
    float* dxw2   = (float*)(ws + 239075328);
    ush*   Y2hi   = (ush*)  (ws + 255852544);       // dxw2^T splits
    ush*   Y2mid  = (ush*)  (ws + 264241152);
    ush*   Y2lo   = (ush*)  (ws + 272629760);
    float* h2     = (float*)(ws + 281018368);
    ush*   H2hi   = (ush*)  (ws + 297795584);       // h2^T splits
    ush*   H2mid  = (ush*)  (ws + 306184192);
    ush*   H2lo   = (ush*)  (ws + 314572800);
    float* xk2    = (float*)(ws + 322961408);
    ush*   A2hi   = (ush*)  (ws + 331350016);       // a2 row-major splits
    ush*   A2mid  = (ush*)  (ws + 335544320);
    ush*   A2lo   = (ush*)  (ws + 339738624);
    float* dxw3   = (float*)(ws + 343932928);
    ush*   Y3hi   = (ush*)  (ws + 352321536);       // dxw3^T splits
    ush*   Y3mid  = (ush*)  (ws + 356515840);
    ush*   Y3lo   = (ush*)  (ws + 360710144);
    float* h3     = (float*)(ws + 364904448);
    float* s1     = (float*)(ws + 373293056);
    int*   idx1   = (int*)  (ws + 373555200);
    float* as1    = (float*)(ws + 373817344);
    float* ad1    = (float*)(ws + 373948416);
    float* dinv_g1= (float*)(ws + 374079488);
    float* dinv_i1= (float*)(ws + 374341632);
    float* dinv_g2= (float*)(ws + 374603776);
    float* dinv_i2= (float*)(ws + 374734848);
    float* x1r    = (float*)(ws + 374865920);
    float* s2     = (float*)(ws + 374996992);
    int*   idx2   = (int*)  (ws + 375128064);
    float* as2    = (float*)(ws + 375193600);
    float* ad2    = (float*)(ws + 375259136);
    float* dinv_g3= (float*)(ws + 375324672);
    float* x2r    = (float*)(ws + 375390208);
    float* x3r    = (float*)(ws + 375521280);

    // stage 1: full graph (N=512), transposed bit-B MFMA aggregations
    k_prep<<<Gg * N1 / 4, 256, 0, stream>>>(adj, dinv_g1, dinv_i1, adjbits);
    k_gemm_rw<<<Gg * N1 / 64, 256, 0, stream>>>(x, W1, dxw1, dinv_g1);
    k_tsplit<N1><<<Gg * 16, 256, 0, stream>>>(dxw1, T1hi, T1mid, T1lo);
    k_aggbT<0><<<512, 256, 0, stream>>>(adjbits, T1hi, T1mid, T1lo, dinv_g1, dxw1, b1, h1, nullptr);
    k_tsplit<N1><<<Gg * 16, 256, 0, stream>>>(h1, T2hi, T2mid, T2lo);
    k_aggbT<1><<<512, 256, 0, stream>>>(adjbits, T2hi, T2mid, T2lo, dinv_i1, h1, nullptr, nullptr, s1);
    k_topk<N1, K1><<<Gg, 256, 0, stream>>>(s1, idx1);
    k_gather<K1><<<Gg * K1 / 4, 256, 0, stream>>>(h1, N1, idx1, att1s, att1d, xk1, as1, ad1);
    k_readout<K1><<<Gg, 128, 0, stream>>>(xk1, x1r);
    k_attn1b<<<Gg * K1 / 4, 256, 0, stream>>>(adjbits, idx1, as1, ad1, a1, A1hi, A1mid, A1lo,
                                              dinv_g2, dinv_i2);

    // stage 2: pooled graph (K1=256), transposed split MFMA
    k_gemm_rw<<<Gg * K1 / 64, 256, 0, stream>>>(xk1, W2, dxw2, dinv_g2);
    k_tsplit<K1><<<Gg * 8, 256, 0, stream>>>(dxw2, Y2hi, Y2mid, Y2lo);
    k_aggsT<K1, 4, 0><<<Gg * 2, 256, 0, stream>>>(Y2hi, Y2mid, Y2lo, A1hi, A1mid, A1lo,
                                                  dinv_g2, dxw2, b2, h2, nullptr);
    k_tsplit<K1><<<Gg * 8, 256, 0, stream>>>(h2, H2hi, H2mid, H2lo);
    k_aggsT<K1, 4, 1><<<Gg * 2, 256, 0, stream>>>(H2hi, H2mid, H2lo, A1hi, A1mid, A1lo,
                                                  dinv_i2, h2, nullptr, nullptr, s2);
    k_topk<K1, K2><<<Gg, 256, 0, stream>>>(s2, idx2);
    k_gather<K2><<<Gg * K2 / 4, 256, 0, stream>>>(h2, K1, idx2, att2s, att2d, xk2, as2, ad2);
    k_readout<K2><<<Gg, 128, 0, stream>>>(xk2, x2r);
    k_attn2<<<Gg * K2 / 4, 256, 0, stream>>>(a1, idx2, as2, ad2, A2hi, A2mid, A2lo, dinv_g3);

    // stage 3: pooled graph (K2=128)
    k_gemm_rw<<<Gg * K2 / 64, 256, 0, stream>>>(xk2, W3, dxw3, dinv_g3);
    k_tsplit<K2><<<Gg * 4, 256, 0, stream>>>(dxw3, Y3hi, Y3mid, Y3lo);
    k_aggsT<K2, 2, 0><<<Gg * 2, 256, 0, stream>>>(Y3hi, Y3mid, Y3lo, A2hi, A2mid, A2lo,
                                                  dinv_g3, dxw3, b3, h3, nullptr);
    k_readout<K2><<<Gg, 128, 0, stream>>>(h3, x3r);

    // final MLP
    k_mlp<<<Gg, 128, 0, stream>>>(x1r, x2r, x3r, Wl1, bl1, Wl2, bl2, Wl3, bl3, out);
}